// Round 3
// baseline (249.310 us; speedup 1.0000x reference)
//
#include <hip/hip_runtime.h>
#include <math.h>

// Problem constants (static graph dims from the reference)
#define BATCH   16384
#define IN_DIM  512
#define NH      128
#define NO      256
#define L2E     1.4426950408889634f

__device__ __forceinline__ float fast_rcp(float x) { return __builtin_amdgcn_rcpf(x); }
__device__ __forceinline__ float fast_exp2(float x) {
#if __has_builtin(__builtin_amdgcn_exp2f)
    return __builtin_amdgcn_exp2f(x);
#else
    return exp2f(x);
#endif
}
__device__ __forceinline__ int rfl(int v) { return __builtin_amdgcn_readfirstlane(v); }

// act ids: 1=identity, 2=tanh, 3=relu, 4=sigmoid. Branchless per-lane select;
// a,k are wave-uniform (SGPR). tanh(z)=1-2/(exp2(2*L2E*z)+1); sig(z)=1/(1+exp2(-L2E*z))
__device__ __forceinline__ float edge_act2(float z, int a, float k) {
    float ex = fast_exp2(k * z);
    float rc = fast_rcp(1.f + ex);
    return (a == 2) ? (1.f - 2.f * rc) : ((a == 4) ? rc : ((a == 3) ? fmaxf(z, 0.f) : z));
}
__device__ __forceinline__ float fast_tanh(float z) {
    float ex = fast_exp2(2.f * L2E * z);
    return 1.f - 2.f * fast_rcp(1.f + ex);
}
__device__ __forceinline__ float act_k(int a) {
    return (a == 2) ? (2.f * L2E) : ((a == 4) ? -L2E : 0.f);
}

__device__ __forceinline__ int lower_bound_dev(const int* arr, int n, int v) {
    int lo = 0, hi = n;
    while (lo < hi) { int m = (lo + hi) >> 1; if (arr[m] < v) lo = m + 1; else hi = m; }
    return lo;
}

// ---------------- fused prep: transpose tiles + CSR offsets + packed edges ----------------
// blocks [0, tile_blocks): 64x64 transpose tiles of x -> xt[IN][B]
// blocks [tile_blocks, ...): edge packing + row-offset binary searches
__global__ __launch_bounds__(256)
void prep_fused(const float* __restrict__ x, float* __restrict__ xt,
                const int* __restrict__ rows_h, const int* __restrict__ cols_h,
                const int* __restrict__ acts_h, const float* __restrict__ wh,
                const int* __restrict__ rows_o, const int* __restrict__ cols_o,
                const int* __restrict__ acts_o, const float* __restrict__ wo,
                int Eh, int Eo, int tile_blocks,
                int* __restrict__ offs_h, int* __restrict__ offs_o,
                int4* __restrict__ packed_h, int4* __restrict__ packed_o) {
    __shared__ float tile[64 * 65];
    if ((int)blockIdx.x < tile_blocks) {
        const int b0 = (blockIdx.x & (BATCH / 64 - 1)) * 64;
        const int c0 = (blockIdx.x / (BATCH / 64)) * 64;
        #pragma unroll
        for (int k = 0; k < 16; ++k) {
            int idx = threadIdx.x + k * 256;
            int r = idx >> 6, c = idx & 63;
            tile[r * 65 + c] = x[(size_t)(b0 + r) * IN_DIM + c0 + c];
        }
        __syncthreads();
        #pragma unroll
        for (int k = 0; k < 16; ++k) {
            int idx = threadIdx.x + k * 256;
            int c = idx >> 6, r = idx & 63;
            xt[(size_t)(c0 + c) * BATCH + b0 + r] = tile[r * 65 + c];
        }
        return;
    }
    int t = (blockIdx.x - tile_blocks) * 256 + threadIdx.x;
    if (t <= NH) offs_h[t] = lower_bound_dev(rows_h, Eh, t);
    else if (t <= NH + 1 + NO) offs_o[t - (NH + 1)] = lower_bound_dev(rows_o, Eo, t - (NH + 1));
    int u = t - (NH + 1 + NO + 1);
    if (u >= 0 && u < Eh)
        packed_h[u] = make_int4(cols_h[u], acts_h[u], __float_as_int(wh[u]), 0);
    u -= Eh;
    if (u >= 0 && u < Eo)
        packed_o[u] = make_int4(cols_o[u], acts_o[u], __float_as_int(wo[u]), 0);
}

// ---------------- hidden: lane covers 4 batch (float4), regs only, no LDS ----------------
// grid (64, 4), block 256 (4 waves). Wave handles 8 hidden rows x 256-batch slice.
__global__ __launch_bounds__(256)
void hidden_kernel(const float* __restrict__ xt, const int* __restrict__ offs_h,
                   const int4* __restrict__ packed_h, float* __restrict__ Ht) {
    const int lane = threadIdx.x & 63;
    const int wv   = threadIdx.x >> 6;
    const int rb   = blockIdx.x * 256;
    const int row0 = blockIdx.y * 32 + wv * 8;
    const int bi   = rb + lane * 4;
    #pragma unroll 1
    for (int r = row0; r < row0 + 8; ++r) {
        const int e0 = rfl(offs_h[r]);
        const int e1 = rfl(offs_h[r + 1]);
        float4 acc = make_float4(0.f, 0.f, 0.f, 0.f);
        #pragma unroll 4
        for (int e = e0; e < e1; ++e) {
            int4 p  = packed_h[e];
            int col = rfl(p.x);
            int a   = rfl(p.y);
            float w = __int_as_float(rfl(p.z));
            float k = act_k(a);
            float4 xv = *(const float4*)&xt[(size_t)col * BATCH + bi];
            acc.x += edge_act2(xv.x * w, a, k);
            acc.y += edge_act2(xv.y * w, a, k);
            acc.z += edge_act2(xv.z * w, a, k);
            acc.w += edge_act2(xv.w * w, a, k);
        }
        *(float4*)&Ht[(size_t)r * BATCH + bi] = acc;
    }
}

// ---------------- output: lane covers 4 batch; OB transpose buffer in LDS ----------------
// grid (64, 4), block 1024 (16 waves). Block: 256-batch slice x 64 output rows.
#define OBS 257      // 256 batch + 1 pad -> conflict-free epilogue column reads
__global__ __launch_bounds__(1024)
void output_kernel(const float* __restrict__ xt, const float* __restrict__ Ht,
                   const int* __restrict__ offs_o, const int4* __restrict__ packed_o,
                   float* __restrict__ out) {
    __shared__ float OB[64 * OBS];   // 65792 B -> 2 blocks/CU
    const int lane = threadIdx.x & 63;
    const int wv   = threadIdx.x >> 6;
    const int rb   = blockIdx.x * 256;
    const int r0   = blockIdx.y * 64;
    const int bi   = rb + lane * 4;
    #pragma unroll 1
    for (int rr = wv * 4; rr < wv * 4 + 4; ++rr) {
        const int r  = r0 + rr;
        const int e0 = rfl(offs_o[r]);
        const int e1 = rfl(offs_o[r + 1]);
        float4 acc = make_float4(0.f, 0.f, 0.f, 0.f);
        #pragma unroll 4
        for (int e = e0; e < e1; ++e) {
            int4 p  = packed_o[e];
            int col = rfl(p.x);
            int a   = rfl(p.y);
            float w = __int_as_float(rfl(p.z));
            float k = act_k(a);
            const float* src = (col < IN_DIM) ? (xt + (size_t)col * BATCH)
                                              : (Ht + (size_t)(col - IN_DIM) * BATCH);
            float4 v = *(const float4*)&src[bi];
            acc.x += edge_act2(v.x * w, a, k);
            acc.y += edge_act2(v.y * w, a, k);
            acc.z += edge_act2(v.z * w, a, k);
            acc.w += edge_act2(v.w * w, a, k);
        }
        // 4 scalar LDS writes (16 total per lane over 4 rows) -- negligible cost
        OB[rr * OBS + lane * 4 + 0] = acc.x;
        OB[rr * OBS + lane * 4 + 1] = acc.y;
        OB[rr * OBS + lane * 4 + 2] = acc.z;
        OB[rr * OBS + lane * 4 + 3] = acc.w;
    }
    __syncthreads();
    // epilogue: out[b][r0+c] = tanh(OB[c][b]); stride-257 LDS reads are conflict-free
    #pragma unroll
    for (int it = 0; it < (256 * 64) / 1024; ++it) {
        int v = threadIdx.x + it * 1024;
        int c = v & 63;
        int b = v >> 6;
        out[(size_t)(rb + b) * NO + r0 + c] = fast_tanh(OB[c * OBS + b]);
    }
}

// ---------------- fallback tiers (previous rounds' correct kernels) ----------------
#define HSTRIDE 65
#define OSTRIDE 65
template <bool USE_XT>
__global__ __launch_bounds__(1024)
void wann_main(const float* __restrict__ xsrc,
               const int* __restrict__ offs_h, const int* __restrict__ offs_o,
               const int4* __restrict__ packed_h, const int4* __restrict__ packed_o,
               float* __restrict__ out) {
    __shared__ float H[NH * HSTRIDE];
    __shared__ float OB2[NO * OSTRIDE];
    const int tid = threadIdx.x, lane = tid & 63, wv = tid >> 6;
    const int rb = blockIdx.x * 64;
    #pragma unroll 1
    for (int r = wv * 8; r < wv * 8 + 8; ++r) {
        int e0 = rfl(offs_h[r]), e1 = rfl(offs_h[r + 1]);
        float acc = 0.f;
        for (int e = e0; e < e1; ++e) {
            int4 p = packed_h[e];
            int col = rfl(p.x), a = rfl(p.y);
            float w = __int_as_float(rfl(p.z));
            float xv = USE_XT ? xsrc[(size_t)col * BATCH + rb + lane]
                              : xsrc[(size_t)(rb + lane) * IN_DIM + col];
            acc += edge_act2(xv * w, a, act_k(a));
        }
        H[r * HSTRIDE + lane] = acc;
    }
    __syncthreads();
    #pragma unroll 1
    for (int r = wv * 16; r < wv * 16 + 16; ++r) {
        int e0 = rfl(offs_o[r]), e1 = rfl(offs_o[r + 1]);
        float acc = 0.f;
        for (int e = e0; e < e1; ++e) {
            int4 p = packed_o[e];
            int col = rfl(p.x), a = rfl(p.y);
            float w = __int_as_float(rfl(p.z));
            float v = (col < IN_DIM)
                    ? (USE_XT ? xsrc[(size_t)col * BATCH + rb + lane]
                              : xsrc[(size_t)(rb + lane) * IN_DIM + col])
                    : H[(col - IN_DIM) * HSTRIDE + lane];
            acc += edge_act2(v * w, a, act_k(a));
        }
        OB2[r * OSTRIDE + lane] = acc;
    }
    __syncthreads();
    #pragma unroll
    for (int it = 0; it < (64 * NO) / 1024; ++it) {
        int v = tid + it * 1024;
        int c = v & 255, r = v >> 8;
        out[(size_t)(rb + r) * NO + c] = fast_tanh(OB2[c * OSTRIDE + r]);
    }
}

extern "C" void kernel_launch(void* const* d_in, const int* in_sizes, int n_in,
                              void* d_out, int out_size, void* d_ws, size_t ws_size,
                              hipStream_t stream) {
    const float* x      = (const float*)d_in[0];
    const float* wh     = (const float*)d_in[1];
    const float* wo     = (const float*)d_in[2];
    const int*   rows_h = (const int*)d_in[3];
    const int*   cols_h = (const int*)d_in[4];
    const int*   acts_h = (const int*)d_in[5];
    const int*   rows_o = (const int*)d_in[6];
    const int*   cols_o = (const int*)d_in[7];
    const int*   acts_o = (const int*)d_in[8];
    float*       out    = (float*)d_out;

    const int Eh = in_sizes[1];
    const int Eo = in_sizes[2];

    // ws layout: [offs_h@0][offs_o@1024][packed_h@4096][packed_o][xt][Ht]
    char* ws = (char*)d_ws;
    int*  offs_h   = (int*)ws;
    int*  offs_o   = (int*)(ws + 1024);
    int4* packed_h = (int4*)(ws + 4096);
    int4* packed_o = packed_h + Eh;
    size_t tier_packed = 4096 + (size_t)(Eh + Eo) * 16;
    size_t xt_off      = (tier_packed + 255) & ~(size_t)255;
    float* xt          = (float*)(ws + xt_off);
    size_t ht_off      = xt_off + (size_t)IN_DIM * BATCH * 4;
    float* Ht          = (float*)(ws + ht_off);
    size_t need_xt     = ht_off;
    size_t need_full   = ht_off + (size_t)NH * BATCH * 4;

    const int ntasks      = (NH + 1) + (NO + 1) + Eh + Eo;
    const int edge_blocks = (ntasks + 255) / 256;
    const int tile_blocks = (BATCH / 64) * (IN_DIM / 64);   // 2048

    if (ws_size >= need_full) {
        prep_fused<<<tile_blocks + edge_blocks, 256, 0, stream>>>(
            x, xt, rows_h, cols_h, acts_h, wh, rows_o, cols_o, acts_o, wo,
            Eh, Eo, tile_blocks, offs_h, offs_o, packed_h, packed_o);
        hidden_kernel<<<dim3(BATCH / 256, 4), 256, 0, stream>>>(xt, offs_h, packed_h, Ht);
        output_kernel<<<dim3(BATCH / 256, 4), 1024, 0, stream>>>(xt, Ht, offs_o, packed_o, out);
    } else if (ws_size >= need_xt) {
        prep_fused<<<tile_blocks + edge_blocks, 256, 0, stream>>>(
            x, xt, rows_h, cols_h, acts_h, wh, rows_o, cols_o, acts_o, wo,
            Eh, Eo, tile_blocks, offs_h, offs_o, packed_h, packed_o);
        wann_main<true><<<BATCH / 64, 1024, 0, stream>>>(xt, offs_h, offs_o, packed_h, packed_o, out);
    } else {
        prep_fused<<<edge_blocks, 256, 0, stream>>>(
            x, (float*)nullptr, rows_h, cols_h, acts_h, wh, rows_o, cols_o, acts_o, wo,
            Eh, Eo, 0, offs_h, offs_o, packed_h, packed_o);
        wann_main<false><<<BATCH / 64, 1024, 0, stream>>>(x, offs_h, offs_o, packed_h, packed_o, out);
    }
}

// Round 4
// 171.835 us; speedup vs baseline: 1.4509x; 1.4509x over previous
//
#include <hip/hip_runtime.h>
#include <math.h>

// Problem constants (static graph dims from the reference)
#define BATCH   16384
#define IN_DIM  512
#define NH      128
#define NO      256
#define L2E     1.4426950408889634f

__device__ __forceinline__ float fast_rcp(float x) { return __builtin_amdgcn_rcpf(x); }
__device__ __forceinline__ float fast_exp2(float x) {
#if __has_builtin(__builtin_amdgcn_exp2f)
    return __builtin_amdgcn_exp2f(x);
#else
    return exp2f(x);
#endif
}
__device__ __forceinline__ int rfl(int v) { return __builtin_amdgcn_readfirstlane(v); }

// act ids: 1=identity, 2=tanh, 3=relu, 4=sigmoid. a,k wave-uniform (SGPR).
// tanh(z)=1-2/(exp2(2*L2E*z)+1); sig(z)=1/(1+exp2(-L2E*z))
__device__ __forceinline__ float edge_act2(float z, int a, float k) {
    float ex = fast_exp2(k * z);
    float rc = fast_rcp(1.f + ex);
    return (a == 2) ? (1.f - 2.f * rc) : ((a == 4) ? rc : ((a == 3) ? fmaxf(z, 0.f) : z));
}
__device__ __forceinline__ float fast_tanh(float z) {
    float ex = fast_exp2(2.f * L2E * z);
    return 1.f - 2.f * fast_rcp(1.f + ex);
}
__device__ __forceinline__ float act_k(int a) {
    return (a == 2) ? (2.f * L2E) : ((a == 4) ? -L2E : 0.f);
}

__device__ __forceinline__ int lower_bound_dev(const int* arr, int n, int v) {
    int lo = 0, hi = n;
    while (lo < hi) { int m = (lo + hi) >> 1; if (arr[m] < v) lo = m + 1; else hi = m; }
    return lo;
}

// ---------------- fused prep: transpose tiles + CSR offsets + packed edges ----------------
__global__ __launch_bounds__(256)
void prep_fused(const float* __restrict__ x, float* __restrict__ xt,
                const int* __restrict__ rows_h, const int* __restrict__ cols_h,
                const int* __restrict__ acts_h, const float* __restrict__ wh,
                const int* __restrict__ rows_o, const int* __restrict__ cols_o,
                const int* __restrict__ acts_o, const float* __restrict__ wo,
                int Eh, int Eo, int tile_blocks,
                int* __restrict__ offs_h, int* __restrict__ offs_o,
                int4* __restrict__ packed_h, int4* __restrict__ packed_o) {
    __shared__ float tile[64 * 65];
    if ((int)blockIdx.x < tile_blocks) {
        const int b0 = (blockIdx.x & (BATCH / 64 - 1)) * 64;
        const int c0 = (blockIdx.x / (BATCH / 64)) * 64;
        #pragma unroll
        for (int k = 0; k < 16; ++k) {
            int idx = threadIdx.x + k * 256;
            int r = idx >> 6, c = idx & 63;
            tile[r * 65 + c] = x[(size_t)(b0 + r) * IN_DIM + c0 + c];
        }
        __syncthreads();
        #pragma unroll
        for (int k = 0; k < 16; ++k) {
            int idx = threadIdx.x + k * 256;
            int c = idx >> 6, r = idx & 63;
            xt[(size_t)(c0 + c) * BATCH + b0 + r] = tile[r * 65 + c];
        }
        return;
    }
    int t = (blockIdx.x - tile_blocks) * 256 + threadIdx.x;
    if (t <= NH) offs_h[t] = lower_bound_dev(rows_h, Eh, t);
    else if (t <= NH + 1 + NO) offs_o[t - (NH + 1)] = lower_bound_dev(rows_o, Eo, t - (NH + 1));
    int u = t - (NH + 1 + NO + 1);
    if (u >= 0 && u < Eh) {
        int a = acts_h[u];
        packed_h[u] = make_int4(cols_h[u], a, __float_as_int(wh[u]), __float_as_int(act_k(a)));
    }
    u -= Eh;
    if (u >= 0 && u < Eo) {
        int a = acts_o[u];
        packed_o[u] = make_int4(cols_o[u], a, __float_as_int(wo[u]), __float_as_int(act_k(a)));
    }
}

// ---------------- hidden: wave = 1 hidden row x 256-batch slice, regs only ----------------
// grid (BATCH/256=64, NH/8=16), block 512 (8 waves) -> 8192 waves = 8/SIMD.
__global__ __launch_bounds__(512)
void hidden_kernel(const float* __restrict__ xt, const int* __restrict__ offs_h,
                   const int4* __restrict__ packed_h, float* __restrict__ Ht) {
    const int lane = threadIdx.x & 63;
    const int wv   = threadIdx.x >> 6;
    const int rb   = blockIdx.x * 256;
    const int bi   = rb + lane * 4;
    const int r    = blockIdx.y * 8 + wv;

    const int e0 = rfl(offs_h[r]);
    const int e1 = rfl(offs_h[r + 1]);
    float4 acc = make_float4(0.f, 0.f, 0.f, 0.f);
    #pragma unroll 4
    for (int e = e0; e < e1; ++e) {
        int4 p  = packed_h[e];
        int col = rfl(p.x);
        int a   = rfl(p.y);
        float w = __int_as_float(rfl(p.z));
        float k = __int_as_float(rfl(p.w));
        float4 xv = *(const float4*)&xt[(size_t)col * BATCH + bi];
        acc.x += edge_act2(xv.x * w, a, k);
        acc.y += edge_act2(xv.y * w, a, k);
        acc.z += edge_act2(xv.z * w, a, k);
        acc.w += edge_act2(xv.w * w, a, k);
    }
    *(float4*)&Ht[(size_t)r * BATCH + bi] = acc;
}

// ---------------- output: wave = 2 output rows x 256-batch slice ----------------
// grid (64, NO/16=16), block 512 (8 waves) -> 8192 waves = 8/SIMD.
// OB stride 260: 16B-aligned rows (260*4=1040=65*16), non-pow2 -> conflict-free.
#define OBS 260
__global__ __launch_bounds__(512)
void output_kernel(const float* __restrict__ xt, const float* __restrict__ Ht,
                   const int* __restrict__ offs_o, const int4* __restrict__ packed_o,
                   float* __restrict__ out) {
    __shared__ float OB[16 * OBS];   // 16.6 KB
    const int lane = threadIdx.x & 63;
    const int wv   = threadIdx.x >> 6;
    const int rb   = blockIdx.x * 256;
    const int r0   = blockIdx.y * 16;
    const int bi   = rb + lane * 4;

    #pragma unroll
    for (int rr = wv * 2; rr < wv * 2 + 2; ++rr) {
        const int r  = r0 + rr;
        const int e0 = rfl(offs_o[r]);
        const int e1 = rfl(offs_o[r + 1]);
        float4 acc = make_float4(0.f, 0.f, 0.f, 0.f);
        #pragma unroll 4
        for (int e = e0; e < e1; ++e) {
            int4 p  = packed_o[e];
            int col = rfl(p.x);
            int a   = rfl(p.y);
            float w = __int_as_float(rfl(p.z));
            float k = __int_as_float(rfl(p.w));
            const float* src = (col < IN_DIM) ? (xt + (size_t)col * BATCH)
                                              : (Ht + (size_t)(col - IN_DIM) * BATCH);
            float4 v = *(const float4*)&src[bi];
            acc.x += edge_act2(v.x * w, a, k);
            acc.y += edge_act2(v.y * w, a, k);
            acc.z += edge_act2(v.z * w, a, k);
            acc.w += edge_act2(v.w * w, a, k);
        }
        *(float4*)&OB[rr * OBS + lane * 4] = acc;
    }
    __syncthreads();
    // epilogue: out[rb+b][r0+c], c in [0,16). 4 lanes cover one b's 64B line.
    #pragma unroll
    for (int it = 0; it < (256 * 16 / 4) / 512; ++it) {
        int v  = threadIdx.x + it * 512;
        int c4 = v & 3;
        int b  = v >> 2;
        float4 o;
        o.x = fast_tanh(OB[(c4 * 4 + 0) * OBS + b]);
        o.y = fast_tanh(OB[(c4 * 4 + 1) * OBS + b]);
        o.z = fast_tanh(OB[(c4 * 4 + 2) * OBS + b]);
        o.w = fast_tanh(OB[(c4 * 4 + 3) * OBS + b]);
        *(float4*)&out[(size_t)(rb + b) * NO + r0 + c4 * 4] = o;
    }
}

// ---------------- fallback tiers (previous rounds' correct kernels) ----------------
#define HSTRIDE 65
#define OSTRIDE 65
template <bool USE_XT>
__global__ __launch_bounds__(1024)
void wann_main(const float* __restrict__ xsrc,
               const int* __restrict__ offs_h, const int* __restrict__ offs_o,
               const int4* __restrict__ packed_h, const int4* __restrict__ packed_o,
               float* __restrict__ out) {
    __shared__ float H[NH * HSTRIDE];
    __shared__ float OB2[NO * OSTRIDE];
    const int tid = threadIdx.x, lane = tid & 63, wv = tid >> 6;
    const int rb = blockIdx.x * 64;
    #pragma unroll 1
    for (int r = wv * 8; r < wv * 8 + 8; ++r) {
        int e0 = rfl(offs_h[r]), e1 = rfl(offs_h[r + 1]);
        float acc = 0.f;
        for (int e = e0; e < e1; ++e) {
            int4 p = packed_h[e];
            int col = rfl(p.x), a = rfl(p.y);
            float w = __int_as_float(rfl(p.z));
            float xv = USE_XT ? xsrc[(size_t)col * BATCH + rb + lane]
                              : xsrc[(size_t)(rb + lane) * IN_DIM + col];
            acc += edge_act2(xv * w, a, act_k(a));
        }
        H[r * HSTRIDE + lane] = acc;
    }
    __syncthreads();
    #pragma unroll 1
    for (int r = wv * 16; r < wv * 16 + 16; ++r) {
        int e0 = rfl(offs_o[r]), e1 = rfl(offs_o[r + 1]);
        float acc = 0.f;
        for (int e = e0; e < e1; ++e) {
            int4 p = packed_o[e];
            int col = rfl(p.x), a = rfl(p.y);
            float w = __int_as_float(rfl(p.z));
            float v = (col < IN_DIM)
                    ? (USE_XT ? xsrc[(size_t)col * BATCH + rb + lane]
                              : xsrc[(size_t)(rb + lane) * IN_DIM + col])
                    : H[(col - IN_DIM) * HSTRIDE + lane];
            acc += edge_act2(v * w, a, act_k(a));
        }
        OB2[r * OSTRIDE + lane] = acc;
    }
    __syncthreads();
    #pragma unroll
    for (int it = 0; it < (64 * NO) / 1024; ++it) {
        int v = tid + it * 1024;
        int c = v & 255, r = v >> 8;
        out[(size_t)(rb + r) * NO + c] = fast_tanh(OB2[c * OSTRIDE + r]);
    }
}

extern "C" void kernel_launch(void* const* d_in, const int* in_sizes, int n_in,
                              void* d_out, int out_size, void* d_ws, size_t ws_size,
                              hipStream_t stream) {
    const float* x      = (const float*)d_in[0];
    const float* wh     = (const float*)d_in[1];
    const float* wo     = (const float*)d_in[2];
    const int*   rows_h = (const int*)d_in[3];
    const int*   cols_h = (const int*)d_in[4];
    const int*   acts_h = (const int*)d_in[5];
    const int*   rows_o = (const int*)d_in[6];
    const int*   cols_o = (const int*)d_in[7];
    const int*   acts_o = (const int*)d_in[8];
    float*       out    = (float*)d_out;

    const int Eh = in_sizes[1];
    const int Eo = in_sizes[2];

    // ws layout: [offs_h@0][offs_o@1024][packed_h@4096][packed_o][xt][Ht]
    char* ws = (char*)d_ws;
    int*  offs_h   = (int*)ws;
    int*  offs_o   = (int*)(ws + 1024);
    int4* packed_h = (int4*)(ws + 4096);
    int4* packed_o = packed_h + Eh;
    size_t tier_packed = 4096 + (size_t)(Eh + Eo) * 16;
    size_t xt_off      = (tier_packed + 255) & ~(size_t)255;
    float* xt          = (float*)(ws + xt_off);
    size_t ht_off      = xt_off + (size_t)IN_DIM * BATCH * 4;
    float* Ht          = (float*)(ws + ht_off);
    size_t need_xt     = ht_off;
    size_t need_full   = ht_off + (size_t)NH * BATCH * 4;

    const int ntasks      = (NH + 1) + (NO + 1) + Eh + Eo;
    const int edge_blocks = (ntasks + 255) / 256;
    const int tile_blocks = (BATCH / 64) * (IN_DIM / 64);   // 2048

    if (ws_size >= need_full) {
        prep_fused<<<tile_blocks + edge_blocks, 256, 0, stream>>>(
            x, xt, rows_h, cols_h, acts_h, wh, rows_o, cols_o, acts_o, wo,
            Eh, Eo, tile_blocks, offs_h, offs_o, packed_h, packed_o);
        hidden_kernel<<<dim3(BATCH / 256, NH / 8), 512, 0, stream>>>(xt, offs_h, packed_h, Ht);
        output_kernel<<<dim3(BATCH / 256, NO / 16), 512, 0, stream>>>(xt, Ht, offs_o, packed_o, out);
    } else if (ws_size >= need_xt) {
        prep_fused<<<tile_blocks + edge_blocks, 256, 0, stream>>>(
            x, xt, rows_h, cols_h, acts_h, wh, rows_o, cols_o, acts_o, wo,
            Eh, Eo, tile_blocks, offs_h, offs_o, packed_h, packed_o);
        wann_main<true><<<BATCH / 64, 1024, 0, stream>>>(xt, offs_h, offs_o, packed_h, packed_o, out);
    } else {
        prep_fused<<<edge_blocks, 256, 0, stream>>>(
            x, (float*)nullptr, rows_h, cols_h, acts_h, wh, rows_o, cols_o, acts_o, wo,
            Eh, Eo, 0, offs_h, offs_o, packed_h, packed_o);
        wann_main<false><<<BATCH / 64, 1024, 0, stream>>>(x, offs_h, offs_o, packed_h, packed_o, out);
    }
}